// Round 1
// baseline (482.767 us; speedup 1.0000x reference)
//
#include <hip/hip_runtime.h>

#define COUT 64
#define KNB 27
#define BN_EPS 1e-5f

// ---------------- Kernel 1: gather-conv + BN-stat accumulation ----------------
// One wave (64 lanes) per output node; lane = output channel.
// Weights w[k][c][lane] (108 floats) held in registers, loaded once per block.
__global__ __launch_bounds__(256) void conv_stats_kernel(
    const float4* __restrict__ x,      // [N_in] rows of 4 floats
    const float*  __restrict__ w,      // [27][4][64]
    const int*    __restrict__ nidx,   // [N_out][27]
    float*        __restrict__ y,      // [N_out][64]  (workspace)
    float*        __restrict__ stats,  // [128]: sum[64], sumsq[64]
    int n_out)
{
    const int lane = threadIdx.x & 63;
    const int wid  = threadIdx.x >> 6;
    const int gwave  = blockIdx.x * 4 + wid;
    const int nwaves = gridDim.x * 4;

    // per-lane weight registers: w[k][c][lane]
    float wr[KNB][4];
#pragma unroll
    for (int k = 0; k < KNB; ++k)
#pragma unroll
        for (int c = 0; c < 4; ++c)
            wr[k][c] = w[(k * 4 + c) * COUT + lane];

    float sum = 0.f, sumsq = 0.f;

    for (int n = gwave; n < n_out; n += nwaves) {
        // coalesced: lanes 0..26 fetch the 27 neighbor indices of node n
        int myidx = (lane < KNB) ? nidx[n * KNB + lane] : 0;
        float acc = 0.f;
#pragma unroll
        for (int k = 0; k < KNB; ++k) {
            int ik = __builtin_amdgcn_readlane(myidx, k);  // SGPR, wave-uniform
            float4 xr = x[ik];                              // uniform 16B load
            acc = fmaf(xr.x, wr[k][0], acc);
            acc = fmaf(xr.y, wr[k][1], acc);
            acc = fmaf(xr.z, wr[k][2], acc);
            acc = fmaf(xr.w, wr[k][3], acc);
        }
        y[(size_t)n * COUT + lane] = acc;   // coalesced 256B per wave
        sum += acc;
        sumsq = fmaf(acc, acc, sumsq);
    }

    // block reduction (4 waves) then one atomic per channel
    __shared__ float red[2][4][COUT];
    red[0][wid][lane] = sum;
    red[1][wid][lane] = sumsq;
    __syncthreads();
    if (threadIdx.x < COUT) {
        int o = threadIdx.x;
        float s  = red[0][0][o] + red[0][1][o] + red[0][2][o] + red[0][3][o];
        float sq = red[1][0][o] + red[1][1][o] + red[1][2][o] + red[1][3][o];
        atomicAdd(&stats[o], s);
        atomicAdd(&stats[COUT + o], sq);
    }
}

// ---------------- Kernel 2: finalize BN affine + write depth output ----------------
__global__ void finalize_kernel(
    const float* __restrict__ stats,
    const float* __restrict__ gamma,
    const float* __restrict__ beta,
    float*       __restrict__ scaleshift,  // [128]: scale[64], shift[64]
    const int*   __restrict__ depth,
    float*       __restrict__ out_tail,    // &out[n_pool*64]
    int n_out, int write_depth)
{
    int o = threadIdx.x;
    if (o < COUT) {
        float invn  = 1.0f / (float)n_out;
        float mean  = stats[o] * invn;
        float var   = stats[COUT + o] * invn - mean * mean;  // population var (ddof=0)
        float scale = gamma[o] * rsqrtf(var + BN_EPS);
        scaleshift[o]        = scale;
        scaleshift[COUT + o] = beta[o] - mean * scale;
    }
    if (o == 0 && write_depth) {
        out_tail[0] = (float)(depth[0] - 2);
    }
}

// ---------------- Kernel 3: affine + ReLU + max-pool over 8 children ----------------
// One wave per pool node, lane = channel. relu(max(a)) == max(relu(a)).
__global__ __launch_bounds__(256) void pool_kernel(
    const float* __restrict__ y,
    const int*   __restrict__ pidx,        // [N_pool][8]
    const float* __restrict__ scaleshift,
    float*       __restrict__ out,
    int n_pool)
{
    const int lane = threadIdx.x & 63;
    const int wid  = threadIdx.x >> 6;
    const int gwave  = blockIdx.x * 4 + wid;
    const int nwaves = gridDim.x * 4;

    const float scale = scaleshift[lane];
    const float shift = scaleshift[COUT + lane];

    for (int n = gwave; n < n_pool; n += nwaves) {
        int myidx = (lane < 8) ? pidx[n * 8 + lane] : 0;
        float m = -INFINITY;
#pragma unroll
        for (int j = 0; j < 8; ++j) {
            int ij = __builtin_amdgcn_readlane(myidx, j);
            float v = y[(size_t)ij * COUT + lane];   // coalesced 256B row
            m = fmaxf(m, fmaf(v, scale, shift));
        }
        out[(size_t)n * COUT + lane] = fmaxf(m, 0.0f);
    }
}

// ---------------- Launch ----------------
extern "C" void kernel_launch(void* const* d_in, const int* in_sizes, int n_in,
                              void* d_out, int out_size, void* d_ws, size_t ws_size,
                              hipStream_t stream)
{
    const float4* x     = (const float4*)d_in[0];
    const float*  w     = (const float*) d_in[1];
    const float*  gamma = (const float*) d_in[2];
    const float*  beta  = (const float*) d_in[3];
    const int*    nidx  = (const int*)   d_in[4];
    const int*    pidx  = (const int*)   d_in[5];
    const int*    depth = (const int*)   d_in[6];

    const int n_out  = in_sizes[4] / KNB;
    const int n_pool = in_sizes[5] / 8;

    float* stats      = (float*)d_ws;                    // 128 f32, zeroed per call
    float* scaleshift = (float*)((char*)d_ws + 512);     // 128 f32
    float* y          = (float*)((char*)d_ws + 1024);    // n_out*64 f32
    float* out        = (float*)d_out;

    hipMemsetAsync(stats, 0, 2 * COUT * sizeof(float), stream);

    conv_stats_kernel<<<2048, 256, 0, stream>>>(x, w, nidx, y, stats, n_out);

    const int write_depth = (out_size > n_pool * COUT) ? 1 : 0;
    finalize_kernel<<<1, 64, 0, stream>>>(stats, gamma, beta, scaleshift,
                                          depth, out + (size_t)n_pool * COUT,
                                          n_out, write_depth);

    pool_kernel<<<1024, 256, 0, stream>>>(y, pidx, scaleshift, out, n_pool);
}

// Round 2
// 401.037 us; speedup vs baseline: 1.2038x; 1.2038x over previous
//
#include <hip/hip_runtime.h>

#define COUT 64
#define KNB 27
#define BN_EPS 1e-5f

// ---------------- Kernel 1: gather-conv + BN-stat accumulation ----------------
// One wave (64 lanes) per output node; lane = output channel.
// Weights w[k][c][lane] (108 floats) held in registers, loaded once per block.
// KEY FIX vs R1: issue ALL 27 neighbor-row gathers before consuming any
// (explicit xr[27] register array, fully unrolled) -> 27 loads in flight per
// wave instead of 1. R1 counters showed g~=1 (fully serialized gather chain).
__global__ __launch_bounds__(256) void conv_stats_kernel(
    const float4* __restrict__ x,      // [N_in] rows of 4 floats
    const float*  __restrict__ w,      // [27][4][64]
    const int*    __restrict__ nidx,   // [N_out][27]
    float*        __restrict__ y,      // [N_out][64]  (workspace)
    float*        __restrict__ stats,  // [128]: sum[64], sumsq[64]
    int n_out)
{
    const int lane = threadIdx.x & 63;
    const int wid  = threadIdx.x >> 6;
    const int gwave  = blockIdx.x * 4 + wid;
    const int nwaves = gridDim.x * 4;

    // per-lane weight registers: w[k][c][lane]
    float wr[KNB][4];
#pragma unroll
    for (int k = 0; k < KNB; ++k)
#pragma unroll
        for (int c = 0; c < 4; ++c)
            wr[k][c] = w[(k * 4 + c) * COUT + lane];

    float sum = 0.f, sumsq = 0.f;

    for (int n = gwave; n < n_out; n += nwaves) {
        // coalesced: lanes 0..26 fetch the 27 neighbor indices of node n
        int myidx = (lane < KNB) ? nidx[n * KNB + lane] : 0;

        // Phase 1: issue all 27 gathers (independent addresses, one wait total)
        float4 xr[27];
#pragma unroll
        for (int k = 0; k < KNB; ++k) {
            int ik = __builtin_amdgcn_readlane(myidx, k);  // SGPR, wave-uniform
            xr[k] = x[ik];                                  // uniform 16B load
        }

        // Phase 2: consume
        float acc = 0.f;
#pragma unroll
        for (int k = 0; k < KNB; ++k) {
            acc = fmaf(xr[k].x, wr[k][0], acc);
            acc = fmaf(xr[k].y, wr[k][1], acc);
            acc = fmaf(xr[k].z, wr[k][2], acc);
            acc = fmaf(xr[k].w, wr[k][3], acc);
        }

        y[(size_t)n * COUT + lane] = acc;   // coalesced 256B per wave
        sum += acc;
        sumsq = fmaf(acc, acc, sumsq);
    }

    // block reduction (4 waves) then one atomic per channel
    __shared__ float red[2][4][COUT];
    red[0][wid][lane] = sum;
    red[1][wid][lane] = sumsq;
    __syncthreads();
    if (threadIdx.x < COUT) {
        int o = threadIdx.x;
        float s  = red[0][0][o] + red[0][1][o] + red[0][2][o] + red[0][3][o];
        float sq = red[1][0][o] + red[1][1][o] + red[1][2][o] + red[1][3][o];
        atomicAdd(&stats[o], s);
        atomicAdd(&stats[COUT + o], sq);
    }
}

// ---------------- Kernel 2: finalize BN affine + write depth output ----------------
__global__ void finalize_kernel(
    const float* __restrict__ stats,
    const float* __restrict__ gamma,
    const float* __restrict__ beta,
    float*       __restrict__ scaleshift,  // [128]: scale[64], shift[64]
    const int*   __restrict__ depth,
    float*       __restrict__ out_tail,    // &out[n_pool*64]
    int n_out, int write_depth)
{
    int o = threadIdx.x;
    if (o < COUT) {
        float invn  = 1.0f / (float)n_out;
        float mean  = stats[o] * invn;
        float var   = stats[COUT + o] * invn - mean * mean;  // population var (ddof=0)
        float scale = gamma[o] * rsqrtf(var + BN_EPS);
        scaleshift[o]        = scale;
        scaleshift[COUT + o] = beta[o] - mean * scale;
    }
    if (o == 0 && write_depth) {
        out_tail[0] = (float)(depth[0] - 2);
    }
}

// ---------------- Kernel 3: affine + ReLU + max-pool over 8 children ----------------
// One wave per pool node, lane = channel. relu(max(a)) == max(relu(a)).
// Loads batched up-front (8 in flight) like conv.
__global__ __launch_bounds__(256) void pool_kernel(
    const float* __restrict__ y,
    const int*   __restrict__ pidx,        // [N_pool][8]
    const float* __restrict__ scaleshift,
    float*       __restrict__ out,
    int n_pool)
{
    const int lane = threadIdx.x & 63;
    const int wid  = threadIdx.x >> 6;
    const int gwave  = blockIdx.x * 4 + wid;
    const int nwaves = gridDim.x * 4;

    const float scale = scaleshift[lane];
    const float shift = scaleshift[COUT + lane];

    for (int n = gwave; n < n_pool; n += nwaves) {
        int myidx = (lane < 8) ? pidx[n * 8 + lane] : 0;
        float v[8];
#pragma unroll
        for (int j = 0; j < 8; ++j) {
            int ij = __builtin_amdgcn_readlane(myidx, j);
            v[j] = y[(size_t)ij * COUT + lane];   // coalesced 256B row
        }
        float m = -INFINITY;
#pragma unroll
        for (int j = 0; j < 8; ++j)
            m = fmaxf(m, fmaf(v[j], scale, shift));
        out[(size_t)n * COUT + lane] = fmaxf(m, 0.0f);
    }
}

// ---------------- Launch ----------------
extern "C" void kernel_launch(void* const* d_in, const int* in_sizes, int n_in,
                              void* d_out, int out_size, void* d_ws, size_t ws_size,
                              hipStream_t stream)
{
    const float4* x     = (const float4*)d_in[0];
    const float*  w     = (const float*) d_in[1];
    const float*  gamma = (const float*) d_in[2];
    const float*  beta  = (const float*) d_in[3];
    const int*    nidx  = (const int*)   d_in[4];
    const int*    pidx  = (const int*)   d_in[5];
    const int*    depth = (const int*)   d_in[6];

    const int n_out  = in_sizes[4] / KNB;
    const int n_pool = in_sizes[5] / 8;

    float* stats      = (float*)d_ws;                    // 128 f32, zeroed per call
    float* scaleshift = (float*)((char*)d_ws + 512);     // 128 f32
    float* y          = (float*)((char*)d_ws + 1024);    // n_out*64 f32
    float* out        = (float*)d_out;

    hipMemsetAsync(stats, 0, 2 * COUT * sizeof(float), stream);

    conv_stats_kernel<<<2048, 256, 0, stream>>>(x, w, nidx, y, stats, n_out);

    const int write_depth = (out_size > n_pool * COUT) ? 1 : 0;
    finalize_kernel<<<1, 64, 0, stream>>>(stats, gamma, beta, scaleshift,
                                          depth, out + (size_t)n_pool * COUT,
                                          n_out, write_depth);

    pool_kernel<<<1024, 256, 0, stream>>>(y, pidx, scaleshift, out, n_pool);
}

// Round 3
// 220.256 us; speedup vs baseline: 2.1918x; 1.8208x over previous
//
#include <hip/hip_runtime.h>

#define COUT 64
#define KNB 27
#define BN_EPS 1e-5f

typedef __attribute__((ext_vector_type(8))) short short8v;  // 8 bf16 (4 VGPRs)
typedef __attribute__((ext_vector_type(4))) float f32x4;

// f32 -> bf16, round-to-nearest-even
static __device__ __forceinline__ short f2bf(float f) {
    unsigned u = __float_as_uint(f);
    return (short)((u + 0x7fffu + ((u >> 16) & 1u)) >> 16);
}

// ---------------- Kernel 1: MFMA gather-conv + BN-stat accumulation ----------------
// Wave owns 16 nodes. A = gathered [16 x 128] (K=108 zero-padded), B = W [128 x 64].
// A-fragment (mfma_f32_16x16x32_bf16): lane holds A[lane&15][kb*32 + (lane>>4)*8 + j],
// j=0..7. k = nb*4+c, so a lane's 8 values = two full x-rows -> 2 per-lane float4
// gathers per K-block. 8 scattered gathers/lane in flight (vs wave-uniform serial).
__global__ __launch_bounds__(256) void conv_stats_kernel(
    const float4* __restrict__ x,      // [N_in] rows of 4 floats
    const float*  __restrict__ w,      // [27][4][64] = [k][c][o], kflat = nb*4+c
    const int*    __restrict__ nidx,   // [N_out][27]
    float*        __restrict__ y,      // [N_out][64]  (workspace)
    float*        __restrict__ stats,  // [128]: sum[64], sumsq[64]
    int n_out)
{
    const int lane = threadIdx.x & 63;
    const int wid  = threadIdx.x >> 6;
    const int row  = lane & 15;   // node within group (A-row / B-col)
    const int grp  = lane >> 4;   // k-chunk selector
    const int gwave  = blockIdx.x * 4 + wid;
    const int nwaves = gridDim.x * 4;
    const int ngroups = (n_out + 15) >> 4;

    // B fragments: bfrag[t][kb], channel o = t*16 + row, k = kb*32 + grp*8 + j.
    // 128 per-lane loads of the 27KB weight (L1/L2-resident), once per wave.
    short8v bfrag[4][4];
#pragma unroll
    for (int t = 0; t < 4; ++t)
#pragma unroll
        for (int kb = 0; kb < 4; ++kb) {
            const int o = t * 16 + row;
#pragma unroll
            for (int j = 0; j < 8; ++j) {
                const int k = kb * 32 + grp * 8 + j;
                float v = (k < KNB * 4) ? w[k * COUT + o] : 0.0f;
                bfrag[t][kb][j] = f2bf(v);
            }
        }

    float sum[4]   = {0.f, 0.f, 0.f, 0.f};
    float sumsq[4] = {0.f, 0.f, 0.f, 0.f};

    for (int g = gwave; g < ngroups; g += nwaves) {
        const int gbase = g << 4;
        const int node  = gbase + row;
        const bool vnode = node < n_out;

        // Phase 1: issue all 8 per-lane index gathers
        int ia[4][2];
#pragma unroll
        for (int kb = 0; kb < 4; ++kb)
#pragma unroll
            for (int h = 0; h < 2; ++h) {
                const int nb = kb * 8 + grp * 2 + h;
                ia[kb][h] = (vnode && nb < KNB) ? nidx[node * KNB + nb] : -1;
            }

        // Phase 2: issue all 8 per-lane x-row gathers (64 scattered req/instr)
        float4 xa[4][2];
#pragma unroll
        for (int kb = 0; kb < 4; ++kb)
#pragma unroll
            for (int h = 0; h < 2; ++h) {
                if (ia[kb][h] >= 0) xa[kb][h] = x[ia[kb][h]];
                else                xa[kb][h] = make_float4(0.f, 0.f, 0.f, 0.f);
            }

        // Phase 3: convert + 16 MFMAs
        f32x4 acc[4];
#pragma unroll
        for (int t = 0; t < 4; ++t) acc[t] = (f32x4){0.f, 0.f, 0.f, 0.f};
#pragma unroll
        for (int kb = 0; kb < 4; ++kb) {
            short8v afrag;
            afrag[0] = f2bf(xa[kb][0].x); afrag[1] = f2bf(xa[kb][0].y);
            afrag[2] = f2bf(xa[kb][0].z); afrag[3] = f2bf(xa[kb][0].w);
            afrag[4] = f2bf(xa[kb][1].x); afrag[5] = f2bf(xa[kb][1].y);
            afrag[6] = f2bf(xa[kb][1].z); afrag[7] = f2bf(xa[kb][1].w);
#pragma unroll
            for (int t = 0; t < 4; ++t)
                acc[t] = __builtin_amdgcn_mfma_f32_16x16x32_bf16(
                             afrag, bfrag[t][kb], acc[t], 0, 0, 0);
        }

        // Phase 4: store y + accumulate stats.
        // C/D layout: col = lane&15 (channel t*16+row), row = grp*4 + j (node).
#pragma unroll
        for (int t = 0; t < 4; ++t) {
#pragma unroll
            for (int j = 0; j < 4; ++j) {
                const int nr = gbase + grp * 4 + j;
                const float v = acc[t][j];
                if (nr < n_out) y[(size_t)nr * COUT + t * 16 + row] = v;
                sum[t]   += v;
                sumsq[t]  = fmaf(v, v, sumsq[t]);
            }
        }
    }

    // Reduce stats: lanes differing in grp hold same channel -> shfl over 16,32,
    // then 4-wave LDS reduction, then one atomicAdd per channel per block.
    __shared__ float redS[4][4][16];
    __shared__ float redQ[4][4][16];
#pragma unroll
    for (int t = 0; t < 4; ++t) {
        float s = sum[t], q = sumsq[t];
        s += __shfl_xor(s, 16); s += __shfl_xor(s, 32);
        q += __shfl_xor(q, 16); q += __shfl_xor(q, 32);
        if (lane < 16) { redS[wid][t][lane] = s; redQ[wid][t][lane] = q; }
    }
    __syncthreads();
    if (threadIdx.x < 128) {
        const int which = threadIdx.x >> 6;       // 0 = sum, 1 = sumsq
        const int o = threadIdx.x & 63;
        const int t = o >> 4, c = o & 15;
        float tot;
        if (which == 0)
            tot = redS[0][t][c] + redS[1][t][c] + redS[2][t][c] + redS[3][t][c];
        else
            tot = redQ[0][t][c] + redQ[1][t][c] + redQ[2][t][c] + redQ[3][t][c];
        atomicAdd(&stats[which * COUT + o], tot);
    }
}

// ---------------- Kernel 2: finalize BN affine + write depth output ----------------
__global__ void finalize_kernel(
    const float* __restrict__ stats,
    const float* __restrict__ gamma,
    const float* __restrict__ beta,
    float*       __restrict__ scaleshift,  // [128]: scale[64], shift[64]
    const int*   __restrict__ depth,
    float*       __restrict__ out_tail,    // &out[n_pool*64]
    int n_out, int write_depth)
{
    int o = threadIdx.x;
    if (o < COUT) {
        float invn  = 1.0f / (float)n_out;
        float mean  = stats[o] * invn;
        float var   = stats[COUT + o] * invn - mean * mean;  // population var
        float scale = gamma[o] * rsqrtf(var + BN_EPS);
        scaleshift[o]        = scale;
        scaleshift[COUT + o] = beta[o] - mean * scale;
    }
    if (o == 0 && write_depth) {
        out_tail[0] = (float)(depth[0] - 2);
    }
}

// ---------------- Kernel 3: affine + ReLU + max-pool over 8 children ----------------
// thread = (pool node, channel-quad). 8 per-lane scattered float4 gathers in
// flight; lanes sharing a node coalesce into full 256B y-rows.
__global__ __launch_bounds__(256) void pool_kernel(
    const float4* __restrict__ y4,         // y as [N_out][16] float4
    const int*    __restrict__ pidx,       // [N_pool][8]
    const float4* __restrict__ scaleshift4,// [32]: scale4[16], shift4[16]
    float4*       __restrict__ out4,       // [N_pool][16]
    int n_pool)
{
    const int t = blockIdx.x * 256 + threadIdx.x;
    const int q = t & 15;
    const int n = t >> 4;
    if (n >= n_pool) return;

    const float4 sc = scaleshift4[q];
    const float4 sh = scaleshift4[16 + q];

    int idx[8];
#pragma unroll
    for (int j = 0; j < 8; ++j) idx[j] = pidx[n * 8 + j];

    float4 v[8];
#pragma unroll
    for (int j = 0; j < 8; ++j) v[j] = y4[(size_t)idx[j] * 16 + q];

    float4 m = make_float4(-INFINITY, -INFINITY, -INFINITY, -INFINITY);
#pragma unroll
    for (int j = 0; j < 8; ++j) {
        m.x = fmaxf(m.x, fmaf(v[j].x, sc.x, sh.x));
        m.y = fmaxf(m.y, fmaf(v[j].y, sc.y, sh.y));
        m.z = fmaxf(m.z, fmaf(v[j].z, sc.z, sh.z));
        m.w = fmaxf(m.w, fmaf(v[j].w, sc.w, sh.w));
    }
    m.x = fmaxf(m.x, 0.f); m.y = fmaxf(m.y, 0.f);
    m.z = fmaxf(m.z, 0.f); m.w = fmaxf(m.w, 0.f);
    out4[(size_t)n * 16 + q] = m;
}

// ---------------- Launch ----------------
extern "C" void kernel_launch(void* const* d_in, const int* in_sizes, int n_in,
                              void* d_out, int out_size, void* d_ws, size_t ws_size,
                              hipStream_t stream)
{
    const float4* x     = (const float4*)d_in[0];
    const float*  w     = (const float*) d_in[1];
    const float*  gamma = (const float*) d_in[2];
    const float*  beta  = (const float*) d_in[3];
    const int*    nidx  = (const int*)   d_in[4];
    const int*    pidx  = (const int*)   d_in[5];
    const int*    depth = (const int*)   d_in[6];

    const int n_out  = in_sizes[4] / KNB;
    const int n_pool = in_sizes[5] / 8;

    float* stats      = (float*)d_ws;                    // 128 f32, zeroed per call
    float* scaleshift = (float*)((char*)d_ws + 512);     // 128 f32
    float* y          = (float*)((char*)d_ws + 1024);    // n_out*64 f32
    float* out        = (float*)d_out;

    hipMemsetAsync(stats, 0, 2 * COUT * sizeof(float), stream);

    conv_stats_kernel<<<2048, 256, 0, stream>>>(x, w, nidx, y, stats, n_out);

    const int write_depth = (out_size > n_pool * COUT) ? 1 : 0;
    finalize_kernel<<<1, 64, 0, stream>>>(stats, gamma, beta, scaleshift,
                                          depth, out + (size_t)n_pool * COUT,
                                          n_out, write_depth);

    const int pool_blocks = (n_pool * 16 + 255) / 256;
    pool_kernel<<<pool_blocks, 256, 0, stream>>>((const float4*)y, pidx,
                                                 (const float4*)scaleshift,
                                                 (float4*)out, n_pool);
}

// Round 4
// 175.461 us; speedup vs baseline: 2.7514x; 1.2553x over previous
//
#include <hip/hip_runtime.h>

#define COUT 64
#define KNB 27
#define BN_EPS 1e-5f

typedef __attribute__((ext_vector_type(8))) short short8v;  // 8 bf16 (4 VGPRs)
typedef __attribute__((ext_vector_type(4))) float f32x4;

union U4S8 { uint4 u; short8v s; };

// f32 -> bf16, round-to-nearest-even
static __device__ __forceinline__ unsigned f2bf(float f) {
    unsigned u = __float_as_uint(f);
    return (u + 0x7fffu + ((u >> 16) & 1u)) >> 16;
}

// ---------------- Kernel 0: pre-convert x rows to packed bf16 ----------------
// xb[i] = 4 bf16 (8B). Halves gather request size, doubles L2-resident fraction.
__global__ __launch_bounds__(256) void xconv_kernel(
    const float4* __restrict__ x, uint2* __restrict__ xb, int n_in)
{
    int i = blockIdx.x * 256 + threadIdx.x;
    if (i >= n_in) return;
    float4 r = x[i];
    uint2 o;
    o.x = f2bf(r.x) | (f2bf(r.y) << 16);
    o.y = f2bf(r.z) | (f2bf(r.w) << 16);
    xb[i] = o;
}

// ---------------- Kernel 1: MFMA gather-conv + BN-stat accumulation ----------------
// Wave owns 16 nodes (A = [16 x 128] zero-padded K, B = W [128 x 64]).
// Changes vs R3: (a) B fragments live in LDS, not 64 VGPRs -> higher occupancy;
// (b) x gathered as packed bf16 (8B rows, no per-element convert);
// (c) next group's 8 index loads prefetched while current gathers are in flight;
// (d) y stored as bf16 (halves write traffic).
__global__ __launch_bounds__(256) void conv_stats_kernel(
    const uint2* __restrict__ xb,      // [N_in] packed bf16 rows
    const float* __restrict__ w,       // [27][4][64]
    const int*   __restrict__ nidx,    // [N_out][27]
    unsigned short* __restrict__ yb,   // [N_out][64] bf16 (workspace)
    float*       __restrict__ stats,   // [128]: sum[64], sumsq[64]
    int n_out)
{
    const int lane = threadIdx.x & 63;
    const int wid  = threadIdx.x >> 6;
    const int row  = lane & 15;   // A-row (node) / B-col (channel) selector
    const int grp  = lane >> 4;   // k-chunk selector
    const int gwave   = blockIdx.x * 4 + wid;
    const int nwaves  = gridDim.x * 4;
    const int ngroups = (n_out + 15) >> 4;

    // ---- stage B fragments into LDS (16 frag-sets x 64 lanes x 16B = 16KB) ----
    __shared__ uint4 blds[16 * 64];
#pragma unroll
    for (int pp = 0; pp < 4; ++pp) {
        const int pair = wid * 4 + pp;        // pair = kb*4 + t
        const int kb = pair >> 2, t = pair & 3;
        const int o = t * 16 + row;
        unsigned e[8];
#pragma unroll
        for (int j = 0; j < 8; ++j) {
            const int k = kb * 32 + grp * 8 + j;
            float v = (k < KNB * 4) ? w[k * COUT + o] : 0.0f;
            e[j] = f2bf(v);
        }
        uint4 f;
        f.x = e[0] | (e[1] << 16);
        f.y = e[2] | (e[3] << 16);
        f.z = e[4] | (e[5] << 16);
        f.w = e[6] | (e[7] << 16);
        blds[pair * 64 + lane] = f;
    }
    __syncthreads();

    float sum[4]   = {0.f, 0.f, 0.f, 0.f};
    float sumsq[4] = {0.f, 0.f, 0.f, 0.f};

    // index loader for group gg (8 per-lane loads, L1-coalesced within group)
    auto load_ia = [&](int gg, int (&ia)[4][2]) {
        const int nodeg = (gg << 4) + row;
        const bool vn = (gg < ngroups) && (nodeg < n_out);
#pragma unroll
        for (int kb = 0; kb < 4; ++kb)
#pragma unroll
            for (int h = 0; h < 2; ++h) {
                const int nb = kb * 8 + grp * 2 + h;
                ia[kb][h] = (vn && nb < KNB) ? nidx[nodeg * KNB + nb] : -1;
            }
    };

    int ia_cur[4][2];
    load_ia(gwave, ia_cur);

    for (int g = gwave; g < ngroups; g += nwaves) {
        // Phase 1: issue all 8 per-lane x-row gathers (bf16-packed, 8B each)
        uint2 xa[4][2];
#pragma unroll
        for (int kb = 0; kb < 4; ++kb)
#pragma unroll
            for (int h = 0; h < 2; ++h) {
                if (ia_cur[kb][h] >= 0) xa[kb][h] = xb[ia_cur[kb][h]];
                else                    xa[kb][h] = make_uint2(0u, 0u);
            }

        // Phase 2: prefetch next group's indices while gathers are in flight
        int ia_nxt[4][2];
        load_ia(g + nwaves, ia_nxt);

        // Phase 3: 16 MFMAs; A-frag = raw packed bits, B-frag from LDS
        f32x4 acc[4];
#pragma unroll
        for (int t = 0; t < 4; ++t) acc[t] = (f32x4){0.f, 0.f, 0.f, 0.f};
#pragma unroll
        for (int kb = 0; kb < 4; ++kb) {
            U4S8 a;
            a.u = make_uint4(xa[kb][0].x, xa[kb][0].y, xa[kb][1].x, xa[kb][1].y);
#pragma unroll
            for (int t = 0; t < 4; ++t) {
                U4S8 b;
                b.u = blds[(kb * 4 + t) * 64 + lane];
                acc[t] = __builtin_amdgcn_mfma_f32_16x16x32_bf16(
                             a.s, b.s, acc[t], 0, 0, 0);
            }
        }

        // Phase 4: store y (bf16) + accumulate stats.
        // C/D layout: channel = t*16 + (lane&15), node = gbase + grp*4 + j.
        const int gbase = g << 4;
#pragma unroll
        for (int t = 0; t < 4; ++t) {
#pragma unroll
            for (int j = 0; j < 4; ++j) {
                const int nr = gbase + grp * 4 + j;
                const float v = acc[t][j];
                if (nr < n_out)
                    yb[(size_t)nr * COUT + t * 16 + row] = (unsigned short)f2bf(v);
                sum[t]   += v;                 // padded rows contribute exact 0
                sumsq[t]  = fmaf(v, v, sumsq[t]);
            }
        }

#pragma unroll
        for (int kb = 0; kb < 4; ++kb)
#pragma unroll
            for (int h = 0; h < 2; ++h) ia_cur[kb][h] = ia_nxt[kb][h];
    }

    // Reduce stats: shfl over grp (16,32), 4-wave LDS reduce, 1 atomic/channel.
    __shared__ float redS[4][4][16];
    __shared__ float redQ[4][4][16];
#pragma unroll
    for (int t = 0; t < 4; ++t) {
        float s = sum[t], q = sumsq[t];
        s += __shfl_xor(s, 16); s += __shfl_xor(s, 32);
        q += __shfl_xor(q, 16); q += __shfl_xor(q, 32);
        if (lane < 16) { redS[wid][t][lane] = s; redQ[wid][t][lane] = q; }
    }
    __syncthreads();
    if (threadIdx.x < 128) {
        const int which = threadIdx.x >> 6;       // 0 = sum, 1 = sumsq
        const int o = threadIdx.x & 63;
        const int t = o >> 4, c = o & 15;
        float tot;
        if (which == 0)
            tot = redS[0][t][c] + redS[1][t][c] + redS[2][t][c] + redS[3][t][c];
        else
            tot = redQ[0][t][c] + redQ[1][t][c] + redQ[2][t][c] + redQ[3][t][c];
        atomicAdd(&stats[which * COUT + o], tot);
    }
}

// ---------------- Kernel 2: finalize BN affine + write depth output ----------------
__global__ void finalize_kernel(
    const float* __restrict__ stats,
    const float* __restrict__ gamma,
    const float* __restrict__ beta,
    float*       __restrict__ scaleshift,  // [128]: scale[64], shift[64]
    const int*   __restrict__ depth,
    float*       __restrict__ out_tail,    // &out[n_pool*64]
    int n_out, int write_depth)
{
    int o = threadIdx.x;
    if (o < COUT) {
        float invn  = 1.0f / (float)n_out;
        float mean  = stats[o] * invn;
        float var   = stats[COUT + o] * invn - mean * mean;  // population var
        float scale = gamma[o] * rsqrtf(var + BN_EPS);
        scaleshift[o]        = scale;
        scaleshift[COUT + o] = beta[o] - mean * scale;
    }
    if (o == 0 && write_depth) {
        out_tail[0] = (float)(depth[0] - 2);
    }
}

// ---------------- Kernel 3: affine + ReLU + max-pool over 8 children ----------------
// thread = (pool node, channel-quad). y rows are bf16 (128B); lanes sharing a
// node coalesce into full rows; 8 scattered 8B gathers in flight per thread.
__global__ __launch_bounds__(256) void pool_kernel(
    const uint2*  __restrict__ yb2,        // y as [N_out][16] packed bf16 quads
    const int*    __restrict__ pidx,       // [N_pool][8]
    const float4* __restrict__ scaleshift4,// [32]: scale4[16], shift4[16]
    float4*       __restrict__ out4,       // [N_pool][16]
    int n_pool)
{
    const int t = blockIdx.x * 256 + threadIdx.x;
    const int q = t & 15;
    const int n = t >> 4;
    if (n >= n_pool) return;

    const float4 sc = scaleshift4[q];
    const float4 sh = scaleshift4[16 + q];

    int idx[8];
#pragma unroll
    for (int j = 0; j < 8; ++j) idx[j] = pidx[n * 8 + j];

    uint2 v[8];
#pragma unroll
    for (int j = 0; j < 8; ++j) v[j] = yb2[(size_t)idx[j] * 16 + q];

    float4 m = make_float4(-INFINITY, -INFINITY, -INFINITY, -INFINITY);
#pragma unroll
    for (int j = 0; j < 8; ++j) {
        float f0 = __uint_as_float(v[j].x << 16);
        float f1 = __uint_as_float(v[j].x & 0xffff0000u);
        float f2 = __uint_as_float(v[j].y << 16);
        float f3 = __uint_as_float(v[j].y & 0xffff0000u);
        m.x = fmaxf(m.x, fmaf(f0, sc.x, sh.x));
        m.y = fmaxf(m.y, fmaf(f1, sc.y, sh.y));
        m.z = fmaxf(m.z, fmaf(f2, sc.z, sh.z));
        m.w = fmaxf(m.w, fmaf(f3, sc.w, sh.w));
    }
    m.x = fmaxf(m.x, 0.f); m.y = fmaxf(m.y, 0.f);
    m.z = fmaxf(m.z, 0.f); m.w = fmaxf(m.w, 0.f);
    out4[(size_t)n * 16 + q] = m;
}

// ---------------- Launch ----------------
extern "C" void kernel_launch(void* const* d_in, const int* in_sizes, int n_in_args,
                              void* d_out, int out_size, void* d_ws, size_t ws_size,
                              hipStream_t stream)
{
    const float4* x     = (const float4*)d_in[0];
    const float*  w     = (const float*) d_in[1];
    const float*  gamma = (const float*) d_in[2];
    const float*  beta  = (const float*) d_in[3];
    const int*    nidx  = (const int*)   d_in[4];
    const int*    pidx  = (const int*)   d_in[5];
    const int*    depth = (const int*)   d_in[6];

    const int n_in   = in_sizes[0] / 4;
    const int n_out  = in_sizes[4] / KNB;
    const int n_pool = in_sizes[5] / 8;

    // workspace layout
    float* stats      = (float*)d_ws;                       // 128 f32
    float* scaleshift = (float*)((char*)d_ws + 512);        // 128 f32
    unsigned short* yb = (unsigned short*)((char*)d_ws + 1024);  // n_out*64 bf16
    size_t yb_bytes   = ((size_t)n_out * COUT * 2 + 255) & ~(size_t)255;
    uint2* xb         = (uint2*)((char*)d_ws + 1024 + yb_bytes); // n_in*8 B
    float* out        = (float*)d_out;

    hipMemsetAsync(stats, 0, 2 * COUT * sizeof(float), stream);

    xconv_kernel<<<(n_in + 255) / 256, 256, 0, stream>>>(x, xb, n_in);

    conv_stats_kernel<<<2048, 256, 0, stream>>>(xb, w, nidx, yb, stats, n_out);

    const int write_depth = (out_size > n_pool * COUT) ? 1 : 0;
    finalize_kernel<<<1, 64, 0, stream>>>(stats, gamma, beta, scaleshift,
                                          depth, out + (size_t)n_pool * COUT,
                                          n_out, write_depth);

    const int pool_blocks = (n_pool * 16 + 255) / 256;
    pool_kernel<<<pool_blocks, 256, 0, stream>>>((const uint2*)yb, pidx,
                                                 (const float4*)scaleshift,
                                                 (float4*)out, n_pool);
}

// Round 5
// 165.574 us; speedup vs baseline: 2.9157x; 1.0597x over previous
//
#include <hip/hip_runtime.h>

#define COUT 64
#define KNB 27
#define BN_EPS 1e-5f
#define NBANDS 6

typedef __attribute__((ext_vector_type(8))) short short8v;  // 8 bf16 (4 VGPRs)
typedef __attribute__((ext_vector_type(4))) float f32x4;

union U4S8 { uint4 u; short8v s; };

// f32 -> bf16, round-to-nearest-even
static __device__ __forceinline__ unsigned f2bf(float f) {
    unsigned u = __float_as_uint(f);
    return (u + 0x7fffu + ((u >> 16) & 1u)) >> 16;
}

// ---------------- Kernel 0: pre-convert x rows to packed bf16 ----------------
__global__ __launch_bounds__(256) void xconv_kernel(
    const float4* __restrict__ x, uint2* __restrict__ xb, int n_in)
{
    int i = blockIdx.x * 256 + threadIdx.x;
    if (i >= n_in) return;
    float4 r = x[i];
    uint2 o;
    o.x = f2bf(r.x) | (f2bf(r.y) << 16);
    o.y = f2bf(r.z) | (f2bf(r.w) << 16);
    xb[i] = o;
}

// ---------------- Kernel 1: banded MFMA gather-conv + BN stats ----------------
// Wave owns 16 nodes. NEW vs R4: gathers are partitioned into NBANDS index
// ranges of ~2MB each; all waves sweep bands in lockstep (vmcnt(0) + raw
// s_barrier pacing) so each XCD's 4MB L2 holds one band at a time. Correctness
// does NOT depend on the barriers (per-wave private data); they only pace.
__global__ __launch_bounds__(256, 4) void conv_stats_kernel(
    const uint2* __restrict__ xb,      // [N_in] packed bf16 rows (8B)
    const float* __restrict__ w,       // [27][4][64]
    const int*   __restrict__ nidx,    // [N_out][27]
    unsigned short* __restrict__ yb,   // [N_out][64] bf16 (workspace)
    float*       __restrict__ stats,   // [128]: sum[64], sumsq[64]
    int n_out, int band)
{
    const int lane = threadIdx.x & 63;
    const int wid  = threadIdx.x >> 6;
    const int row  = lane & 15;   // A-row (node) / B-col (channel) selector
    const int grp  = lane >> 4;   // k-chunk selector
    const int gwave   = blockIdx.x * 4 + wid;
    const int nwaves  = gridDim.x * 4;
    const int ngroups = (n_out + 15) >> 4;
    const int niter   = (ngroups + nwaves - 1) / nwaves;  // uniform trip count

    // ---- stage B fragments into LDS (16 frag-sets x 64 lanes x 16B = 16KB) ----
    __shared__ uint4 blds[16 * 64];
#pragma unroll
    for (int pp = 0; pp < 4; ++pp) {
        const int pair = wid * 4 + pp;        // pair = kb*4 + t
        const int kb = pair >> 2, t = pair & 3;
        const int o = t * 16 + row;
        unsigned e[8];
#pragma unroll
        for (int j = 0; j < 8; ++j) {
            const int k = kb * 32 + grp * 8 + j;
            float v = (k < KNB * 4) ? w[k * COUT + o] : 0.0f;
            e[j] = f2bf(v);
        }
        uint4 f;
        f.x = e[0] | (e[1] << 16);
        f.y = e[2] | (e[3] << 16);
        f.z = e[4] | (e[5] << 16);
        f.w = e[6] | (e[7] << 16);
        blds[pair * 64 + lane] = f;
    }
    __syncthreads();

    float sum[4]   = {0.f, 0.f, 0.f, 0.f};
    float sumsq[4] = {0.f, 0.f, 0.f, 0.f};

    auto load_ia = [&](int gg, int (&ia)[4][2]) {
        const int nodeg = (gg << 4) + row;
        const bool vn = (gg < ngroups) && (nodeg < n_out);
#pragma unroll
        for (int kb = 0; kb < 4; ++kb)
#pragma unroll
            for (int h = 0; h < 2; ++h) {
                const int nb = kb * 8 + grp * 2 + h;
                ia[kb][h] = (vn && nb < KNB) ? nidx[nodeg * KNB + nb] : -1;
            }
    };

    int ia_cur[4][2];
    load_ia(gwave, ia_cur);

    for (int it = 0; it < niter; ++it) {
        const int g = gwave + it * nwaves;   // may exceed ngroups (then ia=-1)

        uint2 xa[4][2];
#pragma unroll
        for (int kb = 0; kb < 4; ++kb)
#pragma unroll
            for (int h = 0; h < 2; ++h) xa[kb][h] = make_uint2(0u, 0u);

        int ia_nxt[4][2];

        // ---- banded gather sweep ----
#pragma unroll
        for (int b = 0; b < NBANDS; ++b) {
            const int lo = b * band;
#pragma unroll
            for (int kb = 0; kb < 4; ++kb)
#pragma unroll
                for (int h = 0; h < 2; ++h) {
                    if ((unsigned)(ia_cur[kb][h] - lo) < (unsigned)band)
                        xa[kb][h] = xb[ia_cur[kb][h]];   // exec-masked gather
                }
            if (b == 0) load_ia(g + nwaves, ia_nxt);  // prefetch during band 0
            // pace: drain this band's gathers, then align block's waves
            asm volatile("s_waitcnt vmcnt(0)" ::: "memory");
            __builtin_amdgcn_s_barrier();
        }

        // ---- 16 MFMAs; A-frag = raw packed bits, B-frag from LDS ----
        f32x4 acc[4];
#pragma unroll
        for (int t = 0; t < 4; ++t) acc[t] = (f32x4){0.f, 0.f, 0.f, 0.f};
#pragma unroll
        for (int kb = 0; kb < 4; ++kb) {
            U4S8 a;
            a.u = make_uint4(xa[kb][0].x, xa[kb][0].y, xa[kb][1].x, xa[kb][1].y);
#pragma unroll
            for (int t = 0; t < 4; ++t) {
                U4S8 b;
                b.u = blds[(kb * 4 + t) * 64 + lane];
                acc[t] = __builtin_amdgcn_mfma_f32_16x16x32_bf16(
                             a.s, b.s, acc[t], 0, 0, 0);
            }
        }

        // ---- store y (bf16) + accumulate stats ----
        // C/D layout: channel = t*16 + (lane&15), node = gbase + grp*4 + j.
        const int gbase = g << 4;
#pragma unroll
        for (int t = 0; t < 4; ++t) {
#pragma unroll
            for (int j = 0; j < 4; ++j) {
                const int nr = gbase + grp * 4 + j;
                const float v = acc[t][j];
                if (nr < n_out)
                    yb[(size_t)nr * COUT + t * 16 + row] = (unsigned short)f2bf(v);
                sum[t]   += v;                 // padded rows contribute exact 0
                sumsq[t]  = fmaf(v, v, sumsq[t]);
            }
        }

#pragma unroll
        for (int kb = 0; kb < 4; ++kb)
#pragma unroll
            for (int h = 0; h < 2; ++h) ia_cur[kb][h] = ia_nxt[kb][h];
    }

    // Reduce stats: shfl over grp (16,32), 4-wave LDS reduce, 1 atomic/channel.
    __shared__ float redS[4][4][16];
    __shared__ float redQ[4][4][16];
#pragma unroll
    for (int t = 0; t < 4; ++t) {
        float s = sum[t], q = sumsq[t];
        s += __shfl_xor(s, 16); s += __shfl_xor(s, 32);
        q += __shfl_xor(q, 16); q += __shfl_xor(q, 32);
        if (lane < 16) { redS[wid][t][lane] = s; redQ[wid][t][lane] = q; }
    }
    __syncthreads();
    if (threadIdx.x < 128) {
        const int which = threadIdx.x >> 6;       // 0 = sum, 1 = sumsq
        const int o = threadIdx.x & 63;
        const int t = o >> 4, c = o & 15;
        float tot;
        if (which == 0)
            tot = redS[0][t][c] + redS[1][t][c] + redS[2][t][c] + redS[3][t][c];
        else
            tot = redQ[0][t][c] + redQ[1][t][c] + redQ[2][t][c] + redQ[3][t][c];
        atomicAdd(&stats[which * COUT + o], tot);
    }
}

// ---------------- Kernel 2: finalize BN affine + write depth output ----------------
__global__ void finalize_kernel(
    const float* __restrict__ stats,
    const float* __restrict__ gamma,
    const float* __restrict__ beta,
    float*       __restrict__ scaleshift,  // [128]: scale[64], shift[64]
    const int*   __restrict__ depth,
    float*       __restrict__ out_tail,    // &out[n_pool*64]
    int n_out, int write_depth)
{
    int o = threadIdx.x;
    if (o < COUT) {
        float invn  = 1.0f / (float)n_out;
        float mean  = stats[o] * invn;
        float var   = stats[COUT + o] * invn - mean * mean;  // population var
        float scale = gamma[o] * rsqrtf(var + BN_EPS);
        scaleshift[o]        = scale;
        scaleshift[COUT + o] = beta[o] - mean * scale;
    }
    if (o == 0 && write_depth) {
        out_tail[0] = (float)(depth[0] - 2);
    }
}

// ---------------- Kernel 3: affine + ReLU + max-pool over 8 children ----------------
__global__ __launch_bounds__(256) void pool_kernel(
    const uint2*  __restrict__ yb2,        // y as [N_out][16] packed bf16 quads
    const int*    __restrict__ pidx,       // [N_pool][8]
    const float4* __restrict__ scaleshift4,// [32]: scale4[16], shift4[16]
    float4*       __restrict__ out4,       // [N_pool][16]
    int n_pool)
{
    const int t = blockIdx.x * 256 + threadIdx.x;
    const int q = t & 15;
    const int n = t >> 4;
    if (n >= n_pool) return;

    const float4 sc = scaleshift4[q];
    const float4 sh = scaleshift4[16 + q];

    int idx[8];
#pragma unroll
    for (int j = 0; j < 8; ++j) idx[j] = pidx[n * 8 + j];

    uint2 v[8];
#pragma unroll
    for (int j = 0; j < 8; ++j) v[j] = yb2[(size_t)idx[j] * 16 + q];

    float4 m = make_float4(-INFINITY, -INFINITY, -INFINITY, -INFINITY);
#pragma unroll
    for (int j = 0; j < 8; ++j) {
        float f0 = __uint_as_float(v[j].x << 16);
        float f1 = __uint_as_float(v[j].x & 0xffff0000u);
        float f2 = __uint_as_float(v[j].y << 16);
        float f3 = __uint_as_float(v[j].y & 0xffff0000u);
        m.x = fmaxf(m.x, fmaf(f0, sc.x, sh.x));
        m.y = fmaxf(m.y, fmaf(f1, sc.y, sh.y));
        m.z = fmaxf(m.z, fmaf(f2, sc.z, sh.z));
        m.w = fmaxf(m.w, fmaf(f3, sc.w, sh.w));
    }
    m.x = fmaxf(m.x, 0.f); m.y = fmaxf(m.y, 0.f);
    m.z = fmaxf(m.z, 0.f); m.w = fmaxf(m.w, 0.f);
    out4[(size_t)n * 16 + q] = m;
}

// ---------------- Launch ----------------
extern "C" void kernel_launch(void* const* d_in, const int* in_sizes, int n_in_args,
                              void* d_out, int out_size, void* d_ws, size_t ws_size,
                              hipStream_t stream)
{
    const float4* x     = (const float4*)d_in[0];
    const float*  w     = (const float*) d_in[1];
    const float*  gamma = (const float*) d_in[2];
    const float*  beta  = (const float*) d_in[3];
    const int*    nidx  = (const int*)   d_in[4];
    const int*    pidx  = (const int*)   d_in[5];
    const int*    depth = (const int*)   d_in[6];

    const int n_in   = in_sizes[0] / 4;
    const int n_out  = in_sizes[4] / KNB;
    const int n_pool = in_sizes[5] / 8;
    const int band   = (n_in + NBANDS - 1) / NBANDS;   // ~250k rows = 2MB

    // workspace layout
    float* stats      = (float*)d_ws;                       // 128 f32
    float* scaleshift = (float*)((char*)d_ws + 512);        // 128 f32
    unsigned short* yb = (unsigned short*)((char*)d_ws + 1024);  // n_out*64 bf16
    size_t yb_bytes   = ((size_t)n_out * COUT * 2 + 255) & ~(size_t)255;
    uint2* xb         = (uint2*)((char*)d_ws + 1024 + yb_bytes); // n_in*8 B
    float* out        = (float*)d_out;

    hipMemsetAsync(stats, 0, 2 * COUT * sizeof(float), stream);

    xconv_kernel<<<(n_in + 255) / 256, 256, 0, stream>>>(x, xb, n_in);

    // ~all blocks co-resident (1 generation) so bands stay phase-aligned
    conv_stats_kernel<<<1024, 256, 0, stream>>>(xb, w, nidx, yb, stats,
                                                n_out, band);

    const int write_depth = (out_size > n_pool * COUT) ? 1 : 0;
    finalize_kernel<<<1, 64, 0, stream>>>(stats, gamma, beta, scaleshift,
                                          depth, out + (size_t)n_pool * COUT,
                                          n_out, write_depth);

    const int pool_blocks = (n_pool * 16 + 255) / 256;
    pool_kernel<<<pool_blocks, 256, 0, stream>>>((const uint2*)yb, pidx,
                                                 (const float4*)scaleshift,
                                                 (float4*)out, n_pool);
}